// Round 1
// baseline (12534.982 us; speedup 1.0000x reference)
//
#include <hip/hip_runtime.h>
#include <math.h>

#define B   256
#define TX  50
#define TY  100
#define NX  64
#define NY  64
#define H   512
#define HOR 60
#define M1  1024
#define M2  512
#define G3  (3*H)        // 1536
#define DIN (2*H + NY)   // 1088

// ---------------------------------------------------------------------------
// Generic fp32 tiled GEMM body: C[M x N] = A[M x K] @ W[N x K]^T (+bias)(relu)
// 64x64 output tile per block, 256 threads, 4x4 per thread, K staged in LDS
// in chunks of 16. Requires M%64==0, N%64==0, K%16==0, all row-major.
// ---------------------------------------------------------------------------
__device__ __forceinline__ void gemm_body(
    const float* __restrict__ A, int lda,
    const float* __restrict__ W, int ldw,
    const float* __restrict__ bias,
    float* __restrict__ C, int ldc,
    int K, int relu)
{
    __shared__ float As[16][68];
    __shared__ float Ws[16][68];
    const int tid = threadIdx.x;      // 256
    const int tx  = tid & 15;         // n dir
    const int ty  = tid >> 4;         // m dir
    const int row0 = blockIdx.y * 64;
    const int col0 = blockIdx.x * 64;
    const int lm = tid >> 2;          // 0..63: tile row (A) / tile col (W)
    const int lk = (tid & 3) << 2;    // 0,4,8,12: k offset

    float acc[4][4];
#pragma unroll
    for (int i = 0; i < 4; ++i)
#pragma unroll
        for (int j = 0; j < 4; ++j) acc[i][j] = 0.f;

    for (int k0 = 0; k0 < K; k0 += 16) {
        float4 av = *(const float4*)(A + (size_t)(row0 + lm) * lda + (k0 + lk));
        float4 wv = *(const float4*)(W + (size_t)(col0 + lm) * ldw + (k0 + lk));
        __syncthreads();
        As[lk + 0][lm] = av.x; As[lk + 1][lm] = av.y;
        As[lk + 2][lm] = av.z; As[lk + 3][lm] = av.w;
        Ws[lk + 0][lm] = wv.x; Ws[lk + 1][lm] = wv.y;
        Ws[lk + 2][lm] = wv.z; Ws[lk + 3][lm] = wv.w;
        __syncthreads();
#pragma unroll
        for (int k = 0; k < 16; ++k) {
            float a[4], w[4];
            *(float4*)a = *(const float4*)&As[k][ty << 2];
            *(float4*)w = *(const float4*)&Ws[k][tx << 2];
#pragma unroll
            for (int i = 0; i < 4; ++i)
#pragma unroll
                for (int j = 0; j < 4; ++j)
                    acc[i][j] = fmaf(a[i], w[j], acc[i][j]);
        }
    }

#pragma unroll
    for (int i = 0; i < 4; ++i) {
        const int r = row0 + (ty << 2) + i;
#pragma unroll
        for (int j = 0; j < 4; ++j) {
            const int c = col0 + (tx << 2) + j;
            float v = acc[i][j];
            if (bias) v += bias[c];
            if (relu) v = v > 0.f ? v : 0.f;
            C[(size_t)r * ldc + c] = v;
        }
    }
}

__global__ __launch_bounds__(256) void gemm64(
    const float* __restrict__ A, int lda,
    const float* __restrict__ W, int ldw,
    const float* __restrict__ bias,
    float* __restrict__ C, int ldc, int K, int relu)
{
    gemm_body(A, lda, W, ldw, bias, C, ldc, K, relu);
}

// ---------------------------------------------------------------------------
// Encoder step: batched GEMMs for up to 4 GRU jobs (xf, xb, ef, eb).
// blockIdx.z = 2*(job-job0) + is_hidden. Writes xg[job] (K=64 input proj,
// +bih) and hg[job] (K=512 hidden proj, +bhh), each B x 3H.
// ---------------------------------------------------------------------------
__global__ __launch_bounds__(256) void enc_gemm(
    const float* __restrict__ x, const float* __restrict__ y,
    const float* __restrict__ Hs,
    const float* w0ih, const float* w0hh, const float* b0ih, const float* b0hh,
    const float* w1ih, const float* w1hh, const float* b1ih, const float* b1hh,
    const float* w2ih, const float* w2hh, const float* b2ih, const float* b2hh,
    const float* w3ih, const float* w3hh, const float* b3ih, const float* b3hh,
    float* __restrict__ xg, float* __restrict__ hg, int t, int job0)
{
    const int z = blockIdx.z;
    const int job = job0 + (z >> 1);
    const int ish = z & 1;

    const float *wih, *whh, *bih, *bhh;
    if (job == 0)      { wih = w0ih; whh = w0hh; bih = b0ih; bhh = b0hh; }
    else if (job == 1) { wih = w1ih; whh = w1hh; bih = b1ih; bhh = b1hh; }
    else if (job == 2) { wih = w2ih; whh = w2hh; bih = b2ih; bhh = b2hh; }
    else               { wih = w3ih; whh = w3hh; bih = b3ih; bhh = b3hh; }

    if (ish) {
        gemm_body(Hs + (size_t)job * B * H, H, whh, H, bhh,
                  hg + (size_t)job * B * G3, G3, H, 0);
    } else {
        const float* src = (job < 2) ? x : y;
        const int T  = (job < 2) ? TX : TY;
        const int tt = (job == 1) ? (TX - 1 - t) : (job == 3) ? (TY - 1 - t) : t;
        gemm_body(src + (size_t)tt * NX, T * NX, wih, NX, bih,
                  xg + (size_t)job * B * G3, G3, NX, 0);
    }
}

__device__ __forceinline__ float sigmoidf_(float v) {
    return 1.f / (1.f + expf(-v));
}

__global__ __launch_bounds__(256) void enc_gates(
    float* __restrict__ Hs, const float* __restrict__ xg,
    const float* __restrict__ hg, int job0)
{
    const int idx = blockIdx.x * 256 + threadIdx.x;
    const int job = job0 + idx / (B * H);
    const int rem = idx % (B * H);
    const int b = rem / H, i = rem % H;
    const float* xp = xg + (size_t)job * B * G3 + (size_t)b * G3;
    const float* hp = hg + (size_t)job * B * G3 + (size_t)b * G3;
    const float xr = xp[i], xz = xp[i + H], xn = xp[i + 2 * H];
    const float hr = hp[i], hz = hp[i + H], hn = hp[i + 2 * H];
    const float r  = sigmoidf_(xr + hr);
    const float zt = sigmoidf_(xz + hz);
    const float n  = tanhf(xn + r * hn);
    float* hsp = Hs + (size_t)job * B * H + rem;
    const float h0 = *hsp;
    *hsp = (1.f - zt) * n + zt * h0;
}

// h_x = hxf + hxb ; h_y = hef + heb ; hcat = [h_x, h_y] ; cz[:, :H] = h_x
__global__ __launch_bounds__(256) void sum_concat(
    const float* __restrict__ Hs, float* __restrict__ hcat, float* __restrict__ cz)
{
    const int idx = blockIdx.x * 256 + threadIdx.x;  // B*H
    const int b = idx / H, i = idx % H;
    const float hx = Hs[idx] + Hs[(size_t)B * H + idx];
    const float hy = Hs[2 * (size_t)B * H + idx] + Hs[3 * (size_t)B * H + idx];
    hcat[(size_t)b * (2 * H) + i] = hx;
    hcat[(size_t)b * (2 * H) + H + i] = hy;
    cz[(size_t)b * (2 * H) + i] = hx;
}

// Decoder GEMM pair: z=0: xgd = y_p @ Wy^T (Wy = d_Wih[:, 2H:], no bias);
//                    z=1: hgd = hd @ d_Whh^T + d_bhh
__global__ __launch_bounds__(256) void dec_gemm(
    const float* __restrict__ yp, int ldyp, const float* __restrict__ hd,
    const float* __restrict__ dWih, const float* __restrict__ dWhh,
    const float* __restrict__ dbhh,
    float* __restrict__ xgd, float* __restrict__ hgd)
{
    if (blockIdx.z == 0) {
        gemm_body(yp, ldyp, dWih + 2 * H, DIN, nullptr, xgd, G3, NY, 0);
    } else {
        gemm_body(hd, H, dWhh, H, dbhh, hgd, G3, H, 0);
    }
}

__global__ __launch_bounds__(256) void dec_gates(
    float* __restrict__ hd, const float* __restrict__ xgd,
    const float* __restrict__ hgd, const float* __restrict__ constb)
{
    const int idx = blockIdx.x * 256 + threadIdx.x;  // B*H
    const int b = idx / H, i = idx % H;
    const float* xp = xgd + (size_t)b * G3;
    const float* cp = constb + (size_t)b * G3;
    const float* hp = hgd + (size_t)b * G3;
    const float xr = xp[i] + cp[i];
    const float xz = xp[i + H] + cp[i + H];
    const float xn = xp[i + 2 * H] + cp[i + 2 * H];
    const float hr = hp[i], hz = hp[i + H], hn = hp[i + 2 * H];
    const float r  = sigmoidf_(xr + hr);
    const float zt = sigmoidf_(xz + hz);
    const float n  = tanhf(xn + r * hn);
    float* hdp = hd + idx;
    const float h0 = *hdp;
    *hdp = (1.f - zt) * n + zt * h0;
}

extern "C" void kernel_launch(void* const* d_in, const int* in_sizes, int n_in,
                              void* d_out, int out_size, void* d_ws, size_t ws_size,
                              hipStream_t stream)
{
    const float* x      = (const float*)d_in[0];
    const float* y      = (const float*)d_in[1];
    const float* xf_Wih = (const float*)d_in[2];
    const float* xf_Whh = (const float*)d_in[3];
    const float* xf_bih = (const float*)d_in[4];
    const float* xf_bhh = (const float*)d_in[5];
    const float* xb_Wih = (const float*)d_in[6];
    const float* xb_Whh = (const float*)d_in[7];
    const float* xb_bih = (const float*)d_in[8];
    const float* xb_bhh = (const float*)d_in[9];
    const float* ef_Wih = (const float*)d_in[10];
    const float* ef_Whh = (const float*)d_in[11];
    const float* ef_bih = (const float*)d_in[12];
    const float* ef_bhh = (const float*)d_in[13];
    const float* eb_Wih = (const float*)d_in[14];
    const float* eb_Whh = (const float*)d_in[15];
    const float* eb_bih = (const float*)d_in[16];
    const float* eb_bhh = (const float*)d_in[17];
    const float* em_W1  = (const float*)d_in[18];
    const float* em_b1  = (const float*)d_in[19];
    const float* em_W2  = (const float*)d_in[20];
    const float* em_b2  = (const float*)d_in[21];
    const float* eo_W   = (const float*)d_in[22];
    const float* eo_b   = (const float*)d_in[23];
    const float* d_Wih  = (const float*)d_in[24];
    const float* d_Whh  = (const float*)d_in[25];
    const float* d_bih  = (const float*)d_in[26];
    const float* d_bhh  = (const float*)d_in[27];
    const float* dm_W1  = (const float*)d_in[28];
    const float* dm_b1  = (const float*)d_in[29];
    const float* dm_W2  = (const float*)d_in[30];
    const float* dm_b2  = (const float*)d_in[31];
    const float* do_W   = (const float*)d_in[32];
    const float* do_b   = (const float*)d_in[33];
    float* out = (float*)d_out;

    float* ws     = (float*)d_ws;
    float* xg     = ws;                      // 4*B*G3
    float* hg     = xg + 4 * (size_t)B * G3; // 4*B*G3
    float* Hs     = hg + 4 * (size_t)B * G3; // 4*B*H
    float* hcat   = Hs + 4 * (size_t)B * H;  // B*2H
    float* h1     = hcat + (size_t)B * 2 * H;// B*M1
    float* h2     = h1 + (size_t)B * M1;     // B*M2
    float* cz     = h2 + (size_t)B * M2;     // B*2H
    float* constb = cz + (size_t)B * 2 * H;  // B*G3
    float* hd     = constb + (size_t)B * G3; // B*H
    float* xgd    = hd + (size_t)B * H;      // B*G3
    float* hgd    = xgd + (size_t)B * G3;    // B*G3
    float* hm1    = hgd + (size_t)B * G3;    // B*M1
    float* hm2    = hm1 + (size_t)B * M1;    // B*M2

    hipMemsetAsync(Hs, 0, sizeof(float) * 4 * (size_t)B * H, stream);
    hipMemsetAsync(hd, 0, sizeof(float) * (size_t)B * H, stream);

    // ---- encoder: 4 GRUs stepped together (xf/xb stop at t=TX) ----
    for (int t = 0; t < TY; ++t) {
        const int job0  = (t < TX) ? 0 : 2;
        const int njobs = (t < TX) ? 4 : 2;
        dim3 g(G3 / 64, B / 64, njobs * 2);
        enc_gemm<<<g, 256, 0, stream>>>(x, y, Hs,
            xf_Wih, xf_Whh, xf_bih, xf_bhh,
            xb_Wih, xb_Whh, xb_bih, xb_bhh,
            ef_Wih, ef_Whh, ef_bih, ef_bhh,
            eb_Wih, eb_Whh, eb_bih, eb_bhh,
            xg, hg, t, job0);
        enc_gates<<<njobs * B * H / 256, 256, 0, stream>>>(Hs, xg, hg, job0);
    }

    // ---- bottleneck MLP ----
    sum_concat<<<B * H / 256, 256, 0, stream>>>(Hs, hcat, cz);
    gemm64<<<dim3(M1 / 64, B / 64), 256, 0, stream>>>(hcat, 2 * H, em_W1, 2 * H, em_b1, h1, M1, 2 * H, 1);
    gemm64<<<dim3(M2 / 64, B / 64), 256, 0, stream>>>(h1, M1, em_W2, M1, em_b2, h2, M2, M1, 1);
    gemm64<<<dim3(H / 64, B / 64), 256, 0, stream>>>(h2, M2, eo_W, M2, eo_b, cz + H, 2 * H, M2, 0);
    gemm64<<<dim3(G3 / 64, B / 64), 256, 0, stream>>>(cz, 2 * H, d_Wih, DIN, d_bih, constb, G3, 2 * H, 0);

    // ---- decoder: 60 sequential steps ----
    for (int t = 0; t < HOR; ++t) {
        const float* yp;
        int ldyp;
        if (t == 0) { yp = x + (size_t)(TX - 1) * NX; ldyp = TX * NX; }
        else        { yp = out + (size_t)(t - 1) * NY; ldyp = HOR * NY; }
        dec_gemm<<<dim3(G3 / 64, B / 64, 2), 256, 0, stream>>>(yp, ldyp, hd, d_Wih, d_Whh, d_bhh, xgd, hgd);
        dec_gates<<<B * H / 256, 256, 0, stream>>>(hd, xgd, hgd, constb);
        gemm64<<<dim3(M1 / 64, B / 64), 256, 0, stream>>>(hd, H, dm_W1, H, dm_b1, hm1, M1, H, 1);
        gemm64<<<dim3(M2 / 64, B / 64), 256, 0, stream>>>(hm1, M1, dm_W2, M1, dm_b2, hm2, M2, M1, 1);
        gemm64<<<dim3(NY / 64, B / 64), 256, 0, stream>>>(hm2, M2, do_W, M2, do_b, out + (size_t)t * NY, HOR * NY, M2, 0);
    }
}

// Round 2
// 8578.870 us; speedup vs baseline: 1.4611x; 1.4611x over previous
//
#include <hip/hip_runtime.h>
#include <math.h>

#define B   256
#define TX  50
#define TY  100
#define NX  64
#define NY  64
#define H   512
#define HOR 60
#define M1  1024
#define M2  512
#define G3  (3*H)        // 1536
#define DIN (2*H + NY)   // 1088

typedef __attribute__((ext_vector_type(8))) short short8;
typedef __attribute__((ext_vector_type(4))) float floatx4;

__device__ __forceinline__ unsigned short f2bf(float f) {
    union { float f; unsigned u; } v; v.f = f;
    return (unsigned short)((v.u + 0x7FFFu + ((v.u >> 16) & 1u)) >> 16);
}

__device__ __forceinline__ void gload_lds16(const void* g, void* lds) {
    __builtin_amdgcn_global_load_lds(
        (const __attribute__((address_space(1))) void*)g,
        (__attribute__((address_space(3))) void*)lds, 16, 0, 0);
}

// ---------------------------------------------------------------------------
// bf16 MFMA GEMM body: C[M x N] = A[M x K] @ W[N x K]^T (+bias)(relu)
// BM x BN tile, 256 threads = 4 waves (2x2), each wave (BM/2)x(BN/2) via
// 16x16x32 MFMA fragments. BK=32, single-buffered LDS, global_load_lds w=16.
// LDS 16B-chunk swizzle: physical_chunk = logical_chunk ^ ((row>>1)&3),
// applied on BOTH the staging source address and the ds_read address.
// Requires M%BM==0, N%BN==0, K%32==0, lda/ldw multiples of 8 elems.
// ---------------------------------------------------------------------------
template<int BM, int BN>
__device__ __forceinline__ void mgemm_body(
    unsigned short* smA, unsigned short* smB,
    const unsigned short* __restrict__ A, int lda, int arow0,
    const unsigned short* __restrict__ W, int ldw, int wrow0,
    const float* __restrict__ bias,
    float* __restrict__ Cf, int ldcf,
    unsigned short* __restrict__ Cb, int ldcb,
    int K, int relu)
{
    constexpr int MF = BM / 32;   // m-fragments per wave
    constexpr int NF = BN / 32;   // n-fragments per wave
    const int tid = threadIdx.x;
    const int w  = tid >> 6, l = tid & 63;
    const int wr = w >> 1, wc = w & 1;
    const int lg = l >> 4, r16 = l & 15;

    floatx4 acc[MF][NF];
#pragma unroll
    for (int m = 0; m < MF; ++m)
#pragma unroll
        for (int n = 0; n < NF; ++n) acc[m][n] = floatx4{0.f, 0.f, 0.f, 0.f};

    for (int k0 = 0; k0 < K; k0 += 32) {
        __syncthreads();   // prior reads of LDS done
#pragma unroll
        for (int i = 0; i < BM / 64; ++i) {
            const int ci = tid + i * 256;          // chunk index (16B units)
            const int row = ci >> 2, pc = ci & 3;  // physical chunk in row
            const int lc = pc ^ ((row >> 1) & 3);  // logical k-chunk
            gload_lds16(A + (size_t)(arow0 + row) * lda + k0 + lc * 8,
                        (char*)smA + w * 1024 + i * 4096);
        }
#pragma unroll
        for (int i = 0; i < BN / 64; ++i) {
            const int ci = tid + i * 256;
            const int row = ci >> 2, pc = ci & 3;
            const int lc = pc ^ ((row >> 1) & 3);
            gload_lds16(W + (size_t)(wrow0 + row) * ldw + k0 + lc * 8,
                        (char*)smB + w * 1024 + i * 4096);
        }
        __syncthreads();   // staging visible (vmcnt drained by barrier)

        short8 af[MF], bfr[NF];
#pragma unroll
        for (int m = 0; m < MF; ++m) {
            const int row = wr * (BM / 2) + m * 16 + r16;
            const int pc = lg ^ ((row >> 1) & 3);
            af[m] = *(const short8*)&smA[row * 32 + pc * 8];
        }
#pragma unroll
        for (int n = 0; n < NF; ++n) {
            const int row = wc * (BN / 2) + n * 16 + r16;
            const int pc = lg ^ ((row >> 1) & 3);
            bfr[n] = *(const short8*)&smB[row * 32 + pc * 8];
        }
#pragma unroll
        for (int m = 0; m < MF; ++m)
#pragma unroll
            for (int n = 0; n < NF; ++n)
                acc[m][n] = __builtin_amdgcn_mfma_f32_16x16x32_bf16(
                    af[m], bfr[n], acc[m][n], 0, 0, 0);
    }

    // epilogue: C/D layout col=lane&15, row=(lane>>4)*4+j  [m89/m91]
#pragma unroll
    for (int m = 0; m < MF; ++m) {
#pragma unroll
        for (int n = 0; n < NF; ++n) {
#pragma unroll
            for (int j = 0; j < 4; ++j) {
                const int r = arow0 + wr * (BM / 2) + m * 16 + lg * 4 + j;
                const int c = wrow0 + wc * (BN / 2) + n * 16 + r16;
                float v = acc[m][n][j];
                if (bias) v += bias[c];
                if (relu && v < 0.f) v = 0.f;
                if (Cf) Cf[(size_t)r * ldcf + c] = v;
                if (Cb) Cb[(size_t)r * ldcb + c] = f2bf(v);
            }
        }
    }
}

template<int BM, int BN>
__global__ __launch_bounds__(256) void k_mgemm(
    const unsigned short* __restrict__ A, int lda,
    const unsigned short* __restrict__ W, int ldw,
    const float* __restrict__ bias,
    float* __restrict__ Cf, int ldcf,
    unsigned short* __restrict__ Cb, int ldcb,
    int K, int relu)
{
    __shared__ __align__(16) unsigned short smA[BM * 32];
    __shared__ __align__(16) unsigned short smB[BN * 32];
    mgemm_body<BM, BN>(smA, smB, A, lda, blockIdx.y * BM,
                       W, ldw, blockIdx.x * BN, bias,
                       Cf, ldcf, Cb, ldcb, K, relu);
}

// ---------------------------------------------------------------------------
// Encoder batched GEMM: blockIdx.z = 2*(job - job0) + is_hidden
// ---------------------------------------------------------------------------
struct EncP {
    const unsigned short *xb, *yb, *Hsb;
    const unsigned short *wih0, *wih1, *wih2, *wih3;
    const unsigned short *whh0, *whh1, *whh2, *whh3;
    const float *bih0, *bih1, *bih2, *bih3;
    const float *bhh0, *bhh1, *bhh2, *bhh3;
    float *xg, *hg;
    int t, job0;
};

__global__ __launch_bounds__(256) void k_enc_gemm(EncP p)
{
    __shared__ __align__(16) unsigned short smA[128 * 32];
    __shared__ __align__(16) unsigned short smB[128 * 32];
    const int z = blockIdx.z;
    const int job = p.job0 + (z >> 1), ish = z & 1;

    const unsigned short *wihj, *whhj;
    const float *bihj, *bhhj;
    if (job == 0)      { wihj = p.wih0; whhj = p.whh0; bihj = p.bih0; bhhj = p.bhh0; }
    else if (job == 1) { wihj = p.wih1; whhj = p.whh1; bihj = p.bih1; bhhj = p.bhh1; }
    else if (job == 2) { wihj = p.wih2; whhj = p.whh2; bihj = p.bih2; bhhj = p.bhh2; }
    else               { wihj = p.wih3; whhj = p.whh3; bihj = p.bih3; bhhj = p.bhh3; }

    const unsigned short *A, *W;
    const float* bias;
    float* Cf;
    int lda, ldw, K;
    if (ish) {
        A = p.Hsb + (size_t)job * B * H; lda = H;
        W = whhj; ldw = H; bias = bhhj;
        Cf = p.hg + (size_t)job * B * G3; K = H;
    } else {
        const int T  = (job < 2) ? TX : TY;
        const int tt = (job == 1) ? (TX - 1 - p.t) : (job == 3) ? (TY - 1 - p.t) : p.t;
        A = ((job < 2) ? p.xb : p.yb) + (size_t)tt * NX; lda = T * NX;
        W = wihj; ldw = NX; bias = bihj;
        Cf = p.xg + (size_t)job * B * G3; K = NX;
    }
    mgemm_body<128, 128>(smA, smB, A, lda, blockIdx.y * 128,
                         W, ldw, blockIdx.x * 128, bias,
                         Cf, G3, nullptr, 0, K, 0);
}

// Decoder GEMM pair: z=0: xgd = y_p @ Wy^T (K=64, no bias);
//                    z=1: hgd = hd @ d_Whh^T + d_bhh (K=512)
__global__ __launch_bounds__(256) void k_dec_gemm(
    const unsigned short* __restrict__ yp, int ldyp,
    const unsigned short* __restrict__ hdb,
    const unsigned short* __restrict__ dWihb,
    const unsigned short* __restrict__ dWhhb,
    const float* __restrict__ dbhh,
    float* __restrict__ xgd, float* __restrict__ hgd)
{
    __shared__ __align__(16) unsigned short smA[128 * 32];
    __shared__ __align__(16) unsigned short smB[128 * 32];
    const unsigned short *A, *W;
    const float* bias;
    float* Cf;
    int lda, ldw, K;
    if (blockIdx.z == 0) {
        A = yp; lda = ldyp; W = dWihb + 2 * H; ldw = DIN;
        bias = nullptr; Cf = xgd; K = NY;
    } else {
        A = hdb; lda = H; W = dWhhb; ldw = H;
        bias = dbhh; Cf = hgd; K = H;
    }
    mgemm_body<128, 128>(smA, smB, A, lda, blockIdx.y * 128,
                         W, ldw, blockIdx.x * 128, bias,
                         Cf, G3, nullptr, 0, K, 0);
}

// ---------------------------------------------------------------------------
// Elementwise kernels
// ---------------------------------------------------------------------------
__device__ __forceinline__ float sigmoidf_(float v) {
    return 1.f / (1.f + expf(-v));
}

__global__ __launch_bounds__(256) void k_cvt(
    const float* __restrict__ in, unsigned short* __restrict__ out, int n)
{
    int i = blockIdx.x * 256 + threadIdx.x;
    const int stride = gridDim.x * 256;
    for (; i < n; i += stride) out[i] = f2bf(in[i]);
}

__global__ __launch_bounds__(256) void k_enc_gates(
    float* __restrict__ Hs, unsigned short* __restrict__ Hsb,
    const float* __restrict__ xg, const float* __restrict__ hg, int job0)
{
    const int idx = blockIdx.x * 256 + threadIdx.x;
    const int job = job0 + idx / (B * H);
    const int rem = idx % (B * H);
    const int b = rem / H, i = rem % H;
    const float* xp = xg + (size_t)job * B * G3 + (size_t)b * G3;
    const float* hp = hg + (size_t)job * B * G3 + (size_t)b * G3;
    const float xr = xp[i], xz = xp[i + H], xn = xp[i + 2 * H];
    const float hr = hp[i], hz = hp[i + H], hn = hp[i + 2 * H];
    const float r  = sigmoidf_(xr + hr);
    const float zt = sigmoidf_(xz + hz);
    const float nn = tanhf(xn + r * hn);
    const size_t o = (size_t)job * B * H + rem;
    const float h0 = Hs[o];
    const float hv = (1.f - zt) * nn + zt * h0;
    Hs[o] = hv;
    Hsb[o] = f2bf(hv);
}

__global__ __launch_bounds__(256) void k_sum_concat(
    const float* __restrict__ Hs,
    unsigned short* __restrict__ hcatb, unsigned short* __restrict__ czb)
{
    const int idx = blockIdx.x * 256 + threadIdx.x;  // B*H
    const int b = idx / H, i = idx % H;
    const float hx = Hs[idx] + Hs[(size_t)B * H + idx];
    const float hy = Hs[2 * (size_t)B * H + idx] + Hs[3 * (size_t)B * H + idx];
    const unsigned short hxb = f2bf(hx);
    hcatb[(size_t)b * (2 * H) + i] = hxb;
    hcatb[(size_t)b * (2 * H) + H + i] = f2bf(hy);
    czb[(size_t)b * (2 * H) + i] = hxb;
}

__global__ __launch_bounds__(256) void k_dec_gates(
    float* __restrict__ hd, unsigned short* __restrict__ hdb,
    const float* __restrict__ xgd, const float* __restrict__ hgd,
    const float* __restrict__ constb)
{
    const int idx = blockIdx.x * 256 + threadIdx.x;  // B*H
    const int b = idx / H, i = idx % H;
    const float* xp = xgd + (size_t)b * G3;
    const float* cp = constb + (size_t)b * G3;
    const float* hp = hgd + (size_t)b * G3;
    const float xr = xp[i] + cp[i];
    const float xz = xp[i + H] + cp[i + H];
    const float xn = xp[i + 2 * H] + cp[i + 2 * H];
    const float hr = hp[i], hz = hp[i + H], hn = hp[i + 2 * H];
    const float r  = sigmoidf_(xr + hr);
    const float zt = sigmoidf_(xz + hz);
    const float nn = tanhf(xn + r * hn);
    const float h0 = hd[idx];
    const float hv = (1.f - zt) * nn + zt * h0;
    hd[idx] = hv;
    hdb[idx] = f2bf(hv);
}

// ---------------------------------------------------------------------------
extern "C" void kernel_launch(void* const* d_in, const int* in_sizes, int n_in,
                              void* d_out, int out_size, void* d_ws, size_t ws_size,
                              hipStream_t stream)
{
    const float* x      = (const float*)d_in[0];
    const float* y      = (const float*)d_in[1];
    const float* xf_bih = (const float*)d_in[4];
    const float* xf_bhh = (const float*)d_in[5];
    const float* xb_bih = (const float*)d_in[8];
    const float* xb_bhh = (const float*)d_in[9];
    const float* ef_bih = (const float*)d_in[12];
    const float* ef_bhh = (const float*)d_in[13];
    const float* eb_bih = (const float*)d_in[16];
    const float* eb_bhh = (const float*)d_in[17];
    const float* em_b1  = (const float*)d_in[19];
    const float* em_b2  = (const float*)d_in[21];
    const float* eo_b   = (const float*)d_in[23];
    const float* d_bih  = (const float*)d_in[26];
    const float* d_bhh  = (const float*)d_in[27];
    const float* dm_b1  = (const float*)d_in[29];
    const float* dm_b2  = (const float*)d_in[31];
    const float* do_b   = (const float*)d_in[33];
    float* out = (float*)d_out;

    // ---- workspace carve-up ----
    float* fp = (float*)d_ws;
    float* xg     = fp; fp += 4 * (size_t)B * G3;
    float* hg     = fp; fp += 4 * (size_t)B * G3;
    float* Hs     = fp; fp += 4 * (size_t)B * H;
    float* constb = fp; fp += (size_t)B * G3;
    float* xgd    = fp; fp += (size_t)B * G3;
    float* hgd    = fp; fp += (size_t)B * G3;
    float* hd     = fp; fp += (size_t)B * H;

    unsigned short* up = (unsigned short*)fp;
    unsigned short* xb16  = up; up += (size_t)B * TX * NX;
    unsigned short* yb16  = up; up += (size_t)B * TY * NY;
    unsigned short* Hsb   = up; up += 4 * (size_t)B * H;
    unsigned short* hdb   = up; up += (size_t)B * H;
    unsigned short* hcatb = up; up += (size_t)B * 2 * H;
    unsigned short* czb   = up; up += (size_t)B * 2 * H;
    unsigned short* h1b   = up; up += (size_t)B * M1;
    unsigned short* h2b   = up; up += (size_t)B * M2;
    unsigned short* hm1b  = up; up += (size_t)B * M1;
    unsigned short* hm2b  = up; up += (size_t)B * M2;
    unsigned short* ypb   = up; up += (size_t)B * NY;

    // bf16 weights: {Wih,Whh}x4, em_W1, em_W2, eo_W, d_Wih, d_Whh, dm_W1, dm_W2, do_W
    const int    widx[16] = {2, 3, 6, 7, 10, 11, 14, 15, 18, 20, 22, 24, 25, 28, 30, 32};
    const size_t wsz[16]  = {
        (size_t)G3 * NX, (size_t)G3 * H, (size_t)G3 * NX, (size_t)G3 * H,
        (size_t)G3 * NX, (size_t)G3 * H, (size_t)G3 * NX, (size_t)G3 * H,
        (size_t)M1 * 2 * H, (size_t)M2 * M1, (size_t)H * M2,
        (size_t)G3 * DIN, (size_t)G3 * H, (size_t)M1 * H, (size_t)M2 * M1,
        (size_t)NY * M2};
    unsigned short* wb[16];
    for (int i = 0; i < 16; ++i) { wb[i] = up; up += wsz[i]; }

    // ---- conversions ----
    for (int i = 0; i < 16; ++i)
        k_cvt<<<512, 256, 0, stream>>>((const float*)d_in[widx[i]], wb[i], (int)wsz[i]);
    k_cvt<<<512, 256, 0, stream>>>(x, xb16, B * TX * NX);
    k_cvt<<<512, 256, 0, stream>>>(y, yb16, B * TY * NY);

    hipMemsetAsync(Hs,  0, sizeof(float) * 4 * (size_t)B * H, stream);
    hipMemsetAsync(hd,  0, sizeof(float) * (size_t)B * H, stream);
    hipMemsetAsync(Hsb, 0, sizeof(unsigned short) * 4 * (size_t)B * H, stream);
    hipMemsetAsync(hdb, 0, sizeof(unsigned short) * (size_t)B * H, stream);

    // ---- encoder: 4 GRUs stepped together (xf/xb stop at t=TX) ----
    EncP p;
    p.xb = xb16; p.yb = yb16; p.Hsb = Hsb;
    p.wih0 = wb[0]; p.whh0 = wb[1]; p.wih1 = wb[2]; p.whh1 = wb[3];
    p.wih2 = wb[4]; p.whh2 = wb[5]; p.wih3 = wb[6]; p.whh3 = wb[7];
    p.bih0 = xf_bih; p.bhh0 = xf_bhh; p.bih1 = xb_bih; p.bhh1 = xb_bhh;
    p.bih2 = ef_bih; p.bhh2 = ef_bhh; p.bih3 = eb_bih; p.bhh3 = eb_bhh;
    p.xg = xg; p.hg = hg;

    for (int t = 0; t < TY; ++t) {
        const int job0  = (t < TX) ? 0 : 2;
        const int njobs = (t < TX) ? 4 : 2;
        p.t = t; p.job0 = job0;
        k_enc_gemm<<<dim3(G3 / 128, B / 128, njobs * 2), 256, 0, stream>>>(p);
        k_enc_gates<<<njobs * B * H / 256, 256, 0, stream>>>(Hs, Hsb, xg, hg, job0);
    }

    // ---- bottleneck MLP ----
    k_sum_concat<<<B * H / 256, 256, 0, stream>>>(Hs, hcatb, czb);
    k_mgemm<128, 128><<<dim3(M1 / 128, B / 128), 256, 0, stream>>>(
        hcatb, 2 * H, wb[8], 2 * H, em_b1, nullptr, 0, h1b, M1, 2 * H, 1);
    k_mgemm<128, 128><<<dim3(M2 / 128, B / 128), 256, 0, stream>>>(
        h1b, M1, wb[9], M1, em_b2, nullptr, 0, h2b, M2, M1, 1);
    k_mgemm<128, 128><<<dim3(H / 128, B / 128), 256, 0, stream>>>(
        h2b, M2, wb[10], M2, eo_b, nullptr, 0, czb + H, 2 * H, M2, 0);
    k_mgemm<128, 128><<<dim3(G3 / 128, B / 128), 256, 0, stream>>>(
        czb, 2 * H, wb[11], DIN, d_bih, constb, G3, nullptr, 0, 2 * H, 0);

    // ---- decoder: 60 sequential steps ----
    for (int t = 0; t < HOR; ++t) {
        const unsigned short* yp;
        int ldyp;
        if (t == 0) { yp = xb16 + (size_t)(TX - 1) * NX; ldyp = TX * NX; }
        else        { yp = ypb; ldyp = NY; }
        k_dec_gemm<<<dim3(G3 / 128, B / 128, 2), 256, 0, stream>>>(
            yp, ldyp, hdb, wb[11], wb[12], d_bhh, xgd, hgd);
        k_dec_gates<<<B * H / 256, 256, 0, stream>>>(hd, hdb, xgd, hgd, constb);
        k_mgemm<128, 128><<<dim3(M1 / 128, B / 128), 256, 0, stream>>>(
            hdb, H, wb[13], H, dm_b1, nullptr, 0, hm1b, M1, H, 1);
        k_mgemm<128, 128><<<dim3(M2 / 128, B / 128), 256, 0, stream>>>(
            hm1b, M1, wb[14], M1, dm_b2, nullptr, 0, hm2b, M2, M1, 1);
        k_mgemm<128, 64><<<dim3(NY / 64, B / 128), 256, 0, stream>>>(
            hm2b, M2, wb[15], M2, do_b, out + (size_t)t * NY, HOR * NY, ypb, NY, M2, 0);
    }
}